// Round 4
// baseline (793.320 us; speedup 1.0000x reference)
//
#include <hip/hip_runtime.h>
#include <math.h>

#define N_USERS 60000
#define N_ITEMS 30000
#define N_NODES 90000
#define DD 64
#define FF 192              // 3*DD
#define FH 96               // FF/2 (bf16 pairs per row)
#define KK_TOT 1408         // 768 + 512 + 128
#define E_UND 500000
#define E_DIR 1000000
#define SCAN_NBLK 88        // ceil(90000/1024)

typedef __attribute__((ext_vector_type(8))) __bf16 bf16x8;
typedef __attribute__((ext_vector_type(8))) unsigned short u16x8;
typedef __attribute__((ext_vector_type(4))) float f32x4;

__device__ __forceinline__ unsigned short f2bf(float f) {
    unsigned int u = __float_as_uint(f);
    unsigned int r = (u + 0x7FFFu + ((u >> 16) & 1u)) >> 16;   // RNE
    return (unsigned short)r;
}
__device__ __forceinline__ float bf_lo(unsigned int x) { return __uint_as_float(x << 16); }
__device__ __forceinline__ float bf_hi(unsigned int x) { return __uint_as_float(x & 0xFFFF0000u); }
__device__ __forceinline__ float bf2f(unsigned short x) {
    return __uint_as_float((unsigned int)x << 16);
}
__device__ __forceinline__ unsigned int pack2(float a, float b) {
    return ((unsigned int)f2bf(b) << 16) | (unsigned int)f2bf(a);
}

// ---------------- edge-layout probe: int32 vs int64 storage ----------------
__global__ void k_mode(const int* __restrict__ ei, int* __restrict__ mode) {
    __shared__ int any;
    if (threadIdx.x == 0) any = 0;
    __syncthreads();
    if (ei[2 * threadIdx.x + 1] != 0) atomicOr(&any, 1);
    __syncthreads();
    if (threadIdx.x == 0) mode[0] = (any == 0) ? 1 : 0;   // 1 => int64 layout
}

__device__ __forceinline__ void load_pair(const int* __restrict__ ei, int md, int u,
                                          int& a, int& b) {
    if (md) { a = ei[2 * u]; b = ei[2 * (E_UND + u)]; }
    else    { a = ei[u];     b = ei[E_UND + u]; }
}

// ---------------- degree count ----------------
__global__ void k_deg(const int* __restrict__ ei, const int* __restrict__ mode,
                      int* __restrict__ deg) {
    int i = blockIdx.x * 256 + threadIdx.x;
    if (i >= E_UND) return;
    int md = mode[0];
    int a, b;
    load_pair(ei, md, i, a, b);
    atomicAdd(&deg[a], 1);
    atomicAdd(&deg[b], 1);
}

// ---------------- exclusive scan (3 kernels) ----------------
__global__ __launch_bounds__(1024) void k_scan1(const int* __restrict__ deg,
                                                int* __restrict__ offs,
                                                int* __restrict__ bsum) {
    __shared__ int tmp[1024];
    int b = blockIdx.x, t = threadIdx.x;
    int i = b * 1024 + t;
    int v = (i < N_NODES) ? deg[i] : 0;
    tmp[t] = v;
    __syncthreads();
    for (int off = 1; off < 1024; off <<= 1) {
        int add = (t >= off) ? tmp[t - off] : 0;
        __syncthreads();
        tmp[t] += add;
        __syncthreads();
    }
    offs[i] = tmp[t] - v;              // exclusive within block
    if (t == 1023) bsum[b] = tmp[t];
}

__global__ void k_scan2(const int* __restrict__ bsum, int* __restrict__ bscan) {
    if (threadIdx.x == 0) {
        int run = 0;
        for (int b = 0; b < SCAN_NBLK; b++) { bscan[b] = run; run += bsum[b]; }
    }
}

__global__ void k_scan3(const int* __restrict__ deg, int* __restrict__ offs,
                        const int* __restrict__ bscan, int* __restrict__ cursor,
                        float* __restrict__ rsq) {
    int i = blockIdx.x * 256 + threadIdx.x;
    if (i >= N_NODES) return;
    int o = offs[i] + bscan[i >> 10];
    offs[i] = o;
    cursor[i] = o;
    int dg = deg[i];
    if (dg < 1) dg = 1;
    rsq[i] = rsqrtf((float)dg);
}

// ---------------- CSR fill (counting-sort scatter, dst only) ----------------
// eval eliminated: edge weight rsq[s]*rsq[d] is factored as rsq[s]*(sum of
// rsq[d]*x[d]) inside the SPMM, so only edst needs scattering (half the
// scattered write-line traffic).
__global__ void k_fill(const int* __restrict__ ei, const int* __restrict__ mode,
                       int* __restrict__ cursor,
                       int* __restrict__ edst) {
    int i = blockIdx.x * 256 + threadIdx.x;
    if (i >= E_DIR) return;
    int md = mode[0];
    int u = (i < E_UND) ? i : i - E_UND;
    int a, b;
    load_pair(ei, md, u, a, b);
    int s, d;
    if (i < E_UND) { s = a; d = b; } else { s = b; d = a; }
    int slot = atomicAdd(&cursor[s], 1);
    edst[slot] = d;
}

// ---------------- user rows: transpose copy into bf16 Xb ----------------
__global__ void k_users(const float* __restrict__ ue, unsigned short* __restrict__ Xbs) {
    int idx = blockIdx.x * 256 + threadIdx.x;
    if (idx >= N_USERS * FF) return;
    int n = idx / FF;
    int r = idx - n * FF;
    int b = r >> 6, d = r & 63;
    Xbs[idx] = f2bf(ue[((size_t)b * N_USERS + n) * DD + d]);
}

// ---------------- W transpose+concat+bf16: Wtb[n][k], n=b*64+d ----------------
__global__ void k_cvt_w(const float* __restrict__ Wt, const float* __restrict__ Wi,
                        const float* __restrict__ Wst, unsigned short* __restrict__ Wtb) {
    int idx = blockIdx.x * 256 + threadIdx.x;
    if (idx >= FF * KK_TOT) return;
    int n = idx / KK_TOT;
    int k = idx - n * KK_TOT;
    int b = n >> 6, d = n & 63;
    float v;
    if (k < 768)       v = Wt [((size_t)b * 768 + k) * 64 + d];
    else if (k < 1280) v = Wi [((size_t)b * 512 + (k - 768)) * 64 + d];
    else               v = Wst[((size_t)b * 128 + (k - 1280)) * 64 + d];
    Wtb[idx] = f2bf(v);
}

// ---------------- W1 transpose to bf16: W1T[n][k] = W1[k][n], 128x192 -------
__global__ void k_cvt_w1(const float* __restrict__ Wu1, const float* __restrict__ Wi1,
                         unsigned short* __restrict__ W1Tu,
                         unsigned short* __restrict__ W1Ti) {
    int idx = blockIdx.x * 256 + threadIdx.x;
    if (idx >= 128 * FF) return;
    int n = idx / FF;
    int k = idx - n * FF;
    W1Tu[idx] = f2bf(Wu1[(size_t)k * 128 + n]);
    W1Ti[idx] = f2bf(Wi1[(size_t)k * 128 + n]);
}

// ---------------- item feature GEMM: all-register, zero-LDS, zero-barrier --
// Each wave loads its own MFMA fragments straight from global to VGPRs.
// No barriers -> no convoy lockstep; the compiler tracks all loads and
// emits counted vmcnt waits itself. Static software pipeline: A (HBM)
// 3-stage / 2-deep, B (L2-resident, 528 KB total) 2-stage at half-K
// granularity. BM=32 rows, 6 waves = (rg 16-rows x ng 64-cols).
#define BM 32
#define NTT (KK_TOT / 64)   // 22 K-steps of 64

__global__ __launch_bounds__(384, 4) void k_item_gemm_reg(
    const float* __restrict__ xt, const float* __restrict__ xi, const float* __restrict__ xs,
    const unsigned short* __restrict__ Wtb,
    const float* __restrict__ bt, const float* __restrict__ bi, const float* __restrict__ bst,
    unsigned short* __restrict__ Xbs) {
    const int tid  = threadIdx.x;
    const int w    = tid >> 6;          // 0..5
    const int lane = tid & 63;
    const int l16  = lane & 15;
    const int quad = lane >> 4;
    const int rg   = w & 1;             // 16-row group
    const int ng   = w >> 1;            // 0..2 (64-col group)
    const int row0 = blockIdx.x * BM;

    int gr = row0 + rg * 16 + l16;
    if (gr >= N_ITEMS) gr = N_ITEMS - 1;   // dup last row; C-write guarded

    // per-lane A base pointers (row + quad folded in; k offsets are
    // compile-time literals < 4096 B so they fold into the load offset)
    const float* at  = xt + (size_t)gr * 768 + quad * 8;
    const float* ai  = xi + (size_t)gr * 512 + quad * 8;
    const float* as_ = xs + (size_t)gr * 128 + quad * 8;

    // per-lane B base pointers, one per 16-col tile
    const unsigned short* bb0 = Wtb + (size_t)(ng * 64 +  0 + l16) * KK_TOT + quad * 8;
    const unsigned short* bb1 = Wtb + (size_t)(ng * 64 + 16 + l16) * KK_TOT + quad * 8;
    const unsigned short* bb2 = Wtb + (size_t)(ng * 64 + 32 + l16) * KK_TOT + quad * 8;
    const unsigned short* bb3 = Wtb + (size_t)(ng * 64 + 48 + l16) * KK_TOT + quad * 8;

    f32x4 acc[4];
#pragma unroll
    for (int tn = 0; tn < 4; tn++) acc[tn] = (f32x4){0.f, 0.f, 0.f, 0.f};

    float4 A[3][2][2];   // [stage][kk-half][j] : 48 VGPRs
    bf16x8 Bf[2][4];     // [half-stage][tn]    : 32 VGPRs

    // A loader for K-step t into stage st (indices must be compile-time)
    auto loadA = [&](int t, int st) {
#pragma unroll
        for (int h = 0; h < 2; h++) {
            int kb = t * 64 + h * 32;           // uniform; 32-span stays in one region
            const float* p;
            if (kb < 768)       p = at  + kb;
            else if (kb < 1280) p = ai  + (kb - 768);
            else                p = as_ + (kb - 1280);
            A[st][h][0] = *(const float4*)(p);
            A[st][h][1] = *(const float4*)(p + 4);
        }
    };
    // B loader for K-half h into half-stage bs
    auto loadB = [&](int h, int bs) {
        int kb = (h >> 1) * 64 + (h & 1) * 32;
        Bf[bs][0] = *(const bf16x8*)(bb0 + kb);
        Bf[bs][1] = *(const bf16x8*)(bb1 + kb);
        Bf[bs][2] = *(const bf16x8*)(bb2 + kb);
        Bf[bs][3] = *(const bf16x8*)(bb3 + kb);
    };

    loadA(0, 0);
    loadB(0, 0);
    loadA(1, 1);

#pragma unroll
    for (int t = 0; t < NTT; t++) {
        const int as3 = t % 3;
#pragma unroll
        for (int h2 = 0; h2 < 2; h2++) {
            const int h  = 2 * t + h2;
            const int bs = h & 1;
            if (h + 1 < 2 * NTT) loadB(h + 1, bs ^ 1);           // 1-deep B
            if (h2 == 0 && t + 2 < NTT) loadA(t + 2, (t + 2) % 3); // 2-deep A
            float4 a0 = A[as3][h2][0];
            float4 a1 = A[as3][h2][1];
            bf16x8 af;
            af[0] = (__bf16)a0.x; af[1] = (__bf16)a0.y;
            af[2] = (__bf16)a0.z; af[3] = (__bf16)a0.w;
            af[4] = (__bf16)a1.x; af[5] = (__bf16)a1.y;
            af[6] = (__bf16)a1.z; af[7] = (__bf16)a1.w;
#pragma unroll
            for (int tn = 0; tn < 4; tn++)
                acc[tn] = __builtin_amdgcn_mfma_f32_16x16x32_bf16(af, Bf[bs][tn], acc[tn], 0, 0, 0);
        }
    }

    // epilogue: bias + bf16 store
#pragma unroll
    for (int tn = 0; tn < 4; tn++) {
        int n = ng * 64 + tn * 16 + l16;    // 0..191
        int b = n >> 6, d = n & 63;
        float bias = bt[b * 64 + d] + bi[b * 64 + d] + bst[b * 64 + d];
#pragma unroll
        for (int r = 0; r < 4; r++) {
            int row = row0 + rg * 16 + quad * 4 + r;
            if (row < N_ITEMS) {
                Xbs[(size_t)(N_USERS + row) * FF + n] = f2bf(acc[tn][r] + bias);
            }
        }
    }
}

// ---------------- SPMM bf16 gather, 4-wide unroll ----------------
// weight factored: y[n] = rsq[n] * sum_d rsq[d] * x[d]; rsq is a 360 KB
// L2-resident table, per-edge value broadcast across the half-block.
__global__ __launch_bounds__(192) void k_spmm_bf(const unsigned int* __restrict__ Xb,
                                                 unsigned int* __restrict__ Yb,
                                                 const int* __restrict__ offs,
                                                 const int* __restrict__ deg,
                                                 const int* __restrict__ edst,
                                                 const float* __restrict__ rsq) {
    int t = threadIdx.x;
    int half = (t >= FH) ? 1 : 0;
    int c = t - half * FH;
    int n = blockIdx.x * 2 + half;
    int start = offs[n];
    int dg = deg[n];
    const int* ed = edst + start;
    float a0 = 0.f, a1 = 0.f;
    for (int j = 0; j < dg; j += 4) {
        int last = dg - 1;
        int j1 = (j + 1 < dg) ? j + 1 : last;
        int j2 = (j + 2 < dg) ? j + 2 : last;
        int j3 = (j + 3 < dg) ? j + 3 : last;
        int d0 = ed[j], d1 = ed[j1], d2 = ed[j2], d3 = ed[j3];
        float v0 = rsq[d0];
        float v1 = (j + 1 < dg) ? rsq[d1] : 0.f;
        float v2 = (j + 2 < dg) ? rsq[d2] : 0.f;
        float v3 = (j + 3 < dg) ? rsq[d3] : 0.f;
        unsigned int x0 = Xb[(size_t)d0 * FH + c];
        unsigned int x1 = Xb[(size_t)d1 * FH + c];
        unsigned int x2 = Xb[(size_t)d2 * FH + c];
        unsigned int x3 = Xb[(size_t)d3 * FH + c];
        a0 = fmaf(v0, bf_lo(x0), a0); a1 = fmaf(v0, bf_hi(x0), a1);
        a0 = fmaf(v1, bf_lo(x1), a0); a1 = fmaf(v1, bf_hi(x1), a1);
        a0 = fmaf(v2, bf_lo(x2), a0); a1 = fmaf(v2, bf_hi(x2), a1);
        a0 = fmaf(v3, bf_lo(x3), a0); a1 = fmaf(v3, bf_hi(x3), a1);
    }
    float rs = rsq[n];
    Yb[(size_t)n * FH + c] = pack2(a0 * rs, a1 * rs);
}

// ---------------- attention: sum 3 bf16 layers + MFMA MLP + readout --------
#define LDA 200

__global__ __launch_bounds__(256) void k_attn_mfma(
    const unsigned int* __restrict__ X0,      // layer-0 bf16 pairs
    const unsigned int* __restrict__ X1,      // layer-1
    const unsigned int* __restrict__ X2,      // layer-2
    const unsigned short* __restrict__ W1T,   // 128 x 192 bf16 (pre-transposed)
    const float* __restrict__ B1,             // 128
    const float* __restrict__ W2,             // 128 x 3
    const float* __restrict__ B2,             // 3
    float* __restrict__ out,
    int node_base, int n_rows) {
    __shared__ unsigned short Atile[64 * LDA];
    __shared__ float aws[64][4];
    const int tid  = threadIdx.x;
    const int wave = tid >> 6;
    const int lane = tid & 63;
    const int row0 = blockIdx.x * 64;
    const float inv3 = 1.f / 3.f;

    // stage A: 64 rows x 96 uint-pairs; sum three bf16 layers in fp32, /3
#pragma unroll
    for (int i = 0; i < 6; i++) {
        int id = tid + i * 256;            // 0..1535
        int r = id / 24;
        int q = id - r * 24;               // uint group: 4 uints = 8 bf16 cols
        u16x8 pk;
        if (row0 + r < n_rows) {
            size_t base = (size_t)(node_base + row0 + r) * FH + q * 4;
            uint4 a = *(const uint4*)(X0 + base);
            uint4 b = *(const uint4*)(X1 + base);
            uint4 c = *(const uint4*)(X2 + base);
            pk[0] = f2bf((bf_lo(a.x) + bf_lo(b.x) + bf_lo(c.x)) * inv3);
            pk[1] = f2bf((bf_hi(a.x) + bf_hi(b.x) + bf_hi(c.x)) * inv3);
            pk[2] = f2bf((bf_lo(a.y) + bf_lo(b.y) + bf_lo(c.y)) * inv3);
            pk[3] = f2bf((bf_hi(a.y) + bf_hi(b.y) + bf_hi(c.y)) * inv3);
            pk[4] = f2bf((bf_lo(a.z) + bf_lo(b.z) + bf_lo(c.z)) * inv3);
            pk[5] = f2bf((bf_hi(a.z) + bf_hi(b.z) + bf_hi(c.z)) * inv3);
            pk[6] = f2bf((bf_lo(a.w) + bf_lo(b.w) + bf_lo(c.w)) * inv3);
            pk[7] = f2bf((bf_hi(a.w) + bf_hi(b.w) + bf_hi(c.w)) * inv3);
        } else {
            pk = (u16x8){0, 0, 0, 0, 0, 0, 0, 0};
        }
        *(u16x8*)(&Atile[r * LDA + q * 8]) = pk;
    }
    __syncthreads();

    f32x4 acc[8];
#pragma unroll
    for (int tn = 0; tn < 8; tn++) acc[tn] = (f32x4){0.f, 0.f, 0.f, 0.f};
    const int l16 = lane & 15;
    const int quad = lane >> 4;
#pragma unroll
    for (int kk = 0; kk < FF; kk += 32) {
        bf16x8 af = *(const bf16x8*)(&Atile[(wave * 16 + l16) * LDA + kk + quad * 8]);
#pragma unroll
        for (int tn = 0; tn < 8; tn++) {
            bf16x8 bf = *(const bf16x8*)(&W1T[(size_t)(tn * 16 + l16) * FF + kk + quad * 8]);
            acc[tn] = __builtin_amdgcn_mfma_f32_16x16x32_bf16(af, bf, acc[tn], 0, 0, 0);
        }
    }

    float pl[4][3];
#pragma unroll
    for (int r = 0; r < 4; r++) { pl[r][0] = 0.f; pl[r][1] = 0.f; pl[r][2] = 0.f; }
#pragma unroll
    for (int tn = 0; tn < 8; tn++) {
        int col = tn * 16 + l16;
        float b1v = B1[col];
        float w0 = W2[col * 3 + 0], w1 = W2[col * 3 + 1], w2v = W2[col * 3 + 2];
#pragma unroll
        for (int r = 0; r < 4; r++) {
            float h = fmaxf(acc[tn][r] + b1v, 0.f);
            pl[r][0] = fmaf(h, w0, pl[r][0]);
            pl[r][1] = fmaf(h, w1, pl[r][1]);
            pl[r][2] = fmaf(h, w2v, pl[r][2]);
        }
    }
#pragma unroll
    for (int m = 1; m <= 8; m <<= 1) {
#pragma unroll
        for (int r = 0; r < 4; r++) {
            pl[r][0] += __shfl_xor(pl[r][0], m, 64);
            pl[r][1] += __shfl_xor(pl[r][1], m, 64);
            pl[r][2] += __shfl_xor(pl[r][2], m, 64);
        }
    }
    float b20 = B2[0], b21 = B2[1], b22 = B2[2];
    if (l16 == 0) {
#pragma unroll
        for (int r = 0; r < 4; r++) {
            float l0 = pl[r][0] + b20, l1 = pl[r][1] + b21, l2 = pl[r][2] + b22;
            float mx = fmaxf(l0, fmaxf(l1, l2));
            float e0 = __expf(l0 - mx), e1 = __expf(l1 - mx), e2 = __expf(l2 - mx);
            float inv = 1.f / (e0 + e1 + e2);
            int rr = wave * 16 + quad * 4 + r;
            aws[rr][0] = e0 * inv; aws[rr][1] = e1 * inv; aws[rr][2] = e2 * inv;
        }
    }
    __syncthreads();

#pragma unroll
    for (int i = 0; i < 16; i++) {
        int flat = tid + i * 256;
        int r = flat >> 6, d = flat & 63;
        if (row0 + r < n_rows) {
            float a0 = aws[r][0], a1 = aws[r][1], a2 = aws[r][2];
            const unsigned short* Ar = &Atile[r * LDA];
            float v = a0 * bf2f(Ar[d]) + a1 * bf2f(Ar[64 + d]) + a2 * bf2f(Ar[128 + d]);
            out[(size_t)(node_base + row0 + r) * DD + d] = v;
        }
    }
}

// ---------------- launch ----------------
extern "C" void kernel_launch(void* const* d_in, const int* in_sizes, int n_in,
                              void* d_out, int out_size, void* d_ws, size_t ws_size,
                              hipStream_t stream) {
    (void)in_sizes; (void)n_in; (void)out_size; (void)ws_size;
    const float* x_txt    = (const float*)d_in[0];
    const float* x_img    = (const float*)d_in[1];
    const float* x_struct = (const float*)d_in[2];
    const float* user_emb = (const float*)d_in[3];
    const float* W_txt    = (const float*)d_in[4];
    const float* b_txt    = (const float*)d_in[5];
    const float* W_img    = (const float*)d_in[6];
    const float* b_img    = (const float*)d_in[7];
    const float* W_st     = (const float*)d_in[8];
    const float* b_st     = (const float*)d_in[9];
    const float* Wu1      = (const float*)d_in[10];
    const float* bu1      = (const float*)d_in[11];
    const float* Wu2      = (const float*)d_in[12];
    const float* bu2      = (const float*)d_in[13];
    const float* Wi1      = (const float*)d_in[14];
    const float* bi1      = (const float*)d_in[15];
    const float* Wi2      = (const float*)d_in[16];
    const float* bi2      = (const float*)d_in[17];
    const int*   ei       = (const int*)d_in[18];
    float* out = (float*)d_out;

    char* base = (char*)d_ws;
    size_t off = 0;
    auto take = [&](size_t bytes) -> void* {
        void* p = base + off;
        off += (bytes + 255) & ~(size_t)255;
        return p;
    };
    unsigned int* Xb0  = (unsigned int*)take((size_t)N_NODES * FH * 4);
    unsigned int* Yb   = (unsigned int*)take((size_t)N_NODES * FH * 4);
    unsigned int* Zb   = (unsigned int*)take((size_t)N_NODES * FH * 4);
    int* deg    = (int*)take((size_t)N_NODES * 4);
    int* offs   = (int*)take((size_t)SCAN_NBLK * 1024 * 4);
    int* cursor = (int*)take((size_t)N_NODES * 4);
    int* bsum   = (int*)take((size_t)SCAN_NBLK * 4);
    int* bscan  = (int*)take((size_t)SCAN_NBLK * 4);
    float* rsq  = (float*)take((size_t)N_NODES * 4);
    int* edst   = (int*)take((size_t)E_DIR * 4);
    int* mode   = (int*)take(256);
    unsigned short* Wtb  = (unsigned short*)take((size_t)FF * KK_TOT * 2);
    unsigned short* W1Tu = (unsigned short*)take((size_t)128 * FF * 2);
    unsigned short* W1Ti = (unsigned short*)take((size_t)128 * FF * 2);

    hipMemsetAsync(deg, 0, (size_t)N_NODES * 4, stream);

    k_mode<<<1, 256, 0, stream>>>(ei, mode);
    k_deg<<<(E_UND + 255) / 256, 256, 0, stream>>>(ei, mode, deg);
    k_scan1<<<SCAN_NBLK, 1024, 0, stream>>>(deg, offs, bsum);
    k_scan2<<<1, 64, 0, stream>>>(bsum, bscan);
    k_scan3<<<(N_NODES + 255) / 256, 256, 0, stream>>>(deg, offs, bscan, cursor, rsq);
    k_fill<<<(E_DIR + 255) / 256, 256, 0, stream>>>(ei, mode, cursor, edst);

    k_users<<<(N_USERS * FF + 255) / 256, 256, 0, stream>>>(user_emb,
                                                            (unsigned short*)Xb0);
    k_cvt_w<<<(FF * KK_TOT + 255) / 256, 256, 0, stream>>>(W_txt, W_img, W_st, Wtb);
    k_cvt_w1<<<(128 * FF + 255) / 256, 256, 0, stream>>>(Wu1, Wi1, W1Tu, W1Ti);
    k_item_gemm_reg<<<(N_ITEMS + BM - 1) / BM, 384, 0, stream>>>(
        x_txt, x_img, x_struct, Wtb, b_txt, b_img, b_st, (unsigned short*)Xb0);

    k_spmm_bf<<<N_NODES / 2, 192, 0, stream>>>(Xb0, Yb, offs, deg, edst, rsq);
    k_spmm_bf<<<N_NODES / 2, 192, 0, stream>>>(Yb, Zb, offs, deg, edst, rsq);

    k_attn_mfma<<<(N_USERS + 63) / 64, 256, 0, stream>>>(
        Xb0, Yb, Zb, W1Tu, bu1, Wu2, bu2, out, 0, N_USERS);
    k_attn_mfma<<<(N_ITEMS + 63) / 64, 256, 0, stream>>>(
        Xb0, Yb, Zb, W1Ti, bi1, Wi2, bi2, out, N_USERS, N_ITEMS);
}

// Round 5
// 791.263 us; speedup vs baseline: 1.0026x; 1.0026x over previous
//
#include <hip/hip_runtime.h>
#include <math.h>

#define N_USERS 60000
#define N_ITEMS 30000
#define N_NODES 90000
#define DD 64
#define FF 192              // 3*DD
#define FH 96               // FF/2 (bf16 pairs per row)
#define KK_TOT 1408         // 768 + 512 + 128
#define E_UND 500000
#define E_DIR 1000000
#define SCAN_NBLK 88        // ceil(90000/1024)

typedef __attribute__((ext_vector_type(8))) __bf16 bf16x8;
typedef __attribute__((ext_vector_type(8))) unsigned short u16x8;
typedef __attribute__((ext_vector_type(4))) float f32x4;

__device__ __forceinline__ unsigned short f2bf(float f) {
    unsigned int u = __float_as_uint(f);
    unsigned int r = (u + 0x7FFFu + ((u >> 16) & 1u)) >> 16;   // RNE
    return (unsigned short)r;
}
__device__ __forceinline__ float bf_lo(unsigned int x) { return __uint_as_float(x << 16); }
__device__ __forceinline__ float bf_hi(unsigned int x) { return __uint_as_float(x & 0xFFFF0000u); }
__device__ __forceinline__ float bf2f(unsigned short x) {
    return __uint_as_float((unsigned int)x << 16);
}
__device__ __forceinline__ unsigned int pack2(float a, float b) {
    return ((unsigned int)f2bf(b) << 16) | (unsigned int)f2bf(a);
}

// ---------------- edge-layout probe: int32 vs int64 storage ----------------
__global__ void k_mode(const int* __restrict__ ei, int* __restrict__ mode) {
    __shared__ int any;
    if (threadIdx.x == 0) any = 0;
    __syncthreads();
    if (ei[2 * threadIdx.x + 1] != 0) atomicOr(&any, 1);
    __syncthreads();
    if (threadIdx.x == 0) mode[0] = (any == 0) ? 1 : 0;   // 1 => int64 layout
}

__device__ __forceinline__ void load_pair(const int* __restrict__ ei, int md, int u,
                                          int& a, int& b) {
    if (md) { a = ei[2 * u]; b = ei[2 * (E_UND + u)]; }
    else    { a = ei[u];     b = ei[E_UND + u]; }
}

// ---------------- degree count ----------------
__global__ void k_deg(const int* __restrict__ ei, const int* __restrict__ mode,
                      int* __restrict__ deg) {
    int i = blockIdx.x * 256 + threadIdx.x;
    if (i >= E_UND) return;
    int md = mode[0];
    int a, b;
    load_pair(ei, md, i, a, b);
    atomicAdd(&deg[a], 1);
    atomicAdd(&deg[b], 1);
}

// ---------------- exclusive scan (3 kernels) ----------------
__global__ __launch_bounds__(1024) void k_scan1(const int* __restrict__ deg,
                                                int* __restrict__ offs,
                                                int* __restrict__ bsum) {
    __shared__ int tmp[1024];
    int b = blockIdx.x, t = threadIdx.x;
    int i = b * 1024 + t;
    int v = (i < N_NODES) ? deg[i] : 0;
    tmp[t] = v;
    __syncthreads();
    for (int off = 1; off < 1024; off <<= 1) {
        int add = (t >= off) ? tmp[t - off] : 0;
        __syncthreads();
        tmp[t] += add;
        __syncthreads();
    }
    offs[i] = tmp[t] - v;              // exclusive within block
    if (t == 1023) bsum[b] = tmp[t];
}

__global__ void k_scan2(const int* __restrict__ bsum, int* __restrict__ bscan) {
    if (threadIdx.x == 0) {
        int run = 0;
        for (int b = 0; b < SCAN_NBLK; b++) { bscan[b] = run; run += bsum[b]; }
    }
}

__global__ void k_scan3(const int* __restrict__ deg, int* __restrict__ offs,
                        const int* __restrict__ bscan, int* __restrict__ cursor,
                        float* __restrict__ rsq) {
    int i = blockIdx.x * 256 + threadIdx.x;
    if (i >= N_NODES) return;
    int o = offs[i] + bscan[i >> 10];
    offs[i] = o;
    cursor[i] = o;
    int dg = deg[i];
    if (dg < 1) dg = 1;
    rsq[i] = rsqrtf((float)dg);
}

// ---------------- CSR fill (counting-sort scatter, dst only) ----------------
__global__ void k_fill(const int* __restrict__ ei, const int* __restrict__ mode,
                       int* __restrict__ cursor,
                       int* __restrict__ edst) {
    int i = blockIdx.x * 256 + threadIdx.x;
    if (i >= E_DIR) return;
    int md = mode[0];
    int u = (i < E_UND) ? i : i - E_UND;
    int a, b;
    load_pair(ei, md, u, a, b);
    int s, d;
    if (i < E_UND) { s = a; d = b; } else { s = b; d = a; }
    int slot = atomicAdd(&cursor[s], 1);
    edst[slot] = d;
}

// ---------------- user rows: transpose copy into bf16 Xb ----------------
__global__ void k_users(const float* __restrict__ ue, unsigned short* __restrict__ Xbs) {
    int idx = blockIdx.x * 256 + threadIdx.x;
    if (idx >= N_USERS * FF) return;
    int n = idx / FF;
    int r = idx - n * FF;
    int b = r >> 6, d = r & 63;
    Xbs[idx] = f2bf(ue[((size_t)b * N_USERS + n) * DD + d]);
}

// ---------------- W transpose+concat+bf16: Wtb[n][k], n=b*64+d ----------------
__global__ void k_cvt_w(const float* __restrict__ Wt, const float* __restrict__ Wi,
                        const float* __restrict__ Wst, unsigned short* __restrict__ Wtb) {
    int idx = blockIdx.x * 256 + threadIdx.x;
    if (idx >= FF * KK_TOT) return;
    int n = idx / KK_TOT;
    int k = idx - n * KK_TOT;
    int b = n >> 6, d = n & 63;
    float v;
    if (k < 768)       v = Wt [((size_t)b * 768 + k) * 64 + d];
    else if (k < 1280) v = Wi [((size_t)b * 512 + (k - 768)) * 64 + d];
    else               v = Wst[((size_t)b * 128 + (k - 1280)) * 64 + d];
    Wtb[idx] = f2bf(v);
}

// ---------------- W1 transpose to bf16: W1T[n][k] = W1[k][n], 128x192 -------
__global__ void k_cvt_w1(const float* __restrict__ Wu1, const float* __restrict__ Wi1,
                         unsigned short* __restrict__ W1Tu,
                         unsigned short* __restrict__ W1Ti) {
    int idx = blockIdx.x * 256 + threadIdx.x;
    if (idx >= 128 * FF) return;
    int n = idx / FF;
    int k = idx - n * FF;
    W1Tu[idx] = f2bf(Wu1[(size_t)k * 128 + n]);
    W1Ti[idx] = f2bf(Wi1[(size_t)k * 128 + n]);
}

// ---------------- item feature GEMM: all-register, zero-LDS, zero-barrier --
// r4 retry with bulletproof codegen: NO arrays, NO lambdas — named registers
// and literal-index macros only (rule #20: runtime-indexed ext-vector arrays
// went to scratch in r4, VGPR_Count=32 proved it). 2-bank software pipeline,
// banks alternate via macro token names; compiler emits counted vmcnt.
#define BM 32
#define NTT (KK_TOT / 64)   // 22 K-steps of 64

#define MFMA_ __builtin_amdgcn_mfma_f32_16x16x32_bf16

#define LOADA(t, a0, a1, a2, a3) do {                                   \
    const float* p_;                                                    \
    if ((t)*64 < 768)        p_ = at  + (t)*64;                         \
    else if ((t)*64 < 1280)  p_ = ai  + ((t)*64 - 768);                 \
    else                     p_ = as_ + ((t)*64 - 1280);                \
    a0 = *(const float4*)(p_);      a1 = *(const float4*)(p_ + 4);      \
    a2 = *(const float4*)(p_ + 32); a3 = *(const float4*)(p_ + 36);     \
} while (0)

#define LOADB(t, b0, b1, b2, b3, b4, b5, b6, b7) do {                   \
    b0 = *(const bf16x8*)(bb0 + (t)*64);                                \
    b1 = *(const bf16x8*)(bb0 + (t)*64 + 32);                           \
    b2 = *(const bf16x8*)(bb1 + (t)*64);                                \
    b3 = *(const bf16x8*)(bb1 + (t)*64 + 32);                           \
    b4 = *(const bf16x8*)(bb2 + (t)*64);                                \
    b5 = *(const bf16x8*)(bb2 + (t)*64 + 32);                           \
    b6 = *(const bf16x8*)(bb3 + (t)*64);                                \
    b7 = *(const bf16x8*)(bb3 + (t)*64 + 32);                           \
} while (0)

#define CVT8(af, lo, hi) do {                                           \
    af[0] = (__bf16)lo.x; af[1] = (__bf16)lo.y;                         \
    af[2] = (__bf16)lo.z; af[3] = (__bf16)lo.w;                         \
    af[4] = (__bf16)hi.x; af[5] = (__bf16)hi.y;                         \
    af[6] = (__bf16)hi.z; af[7] = (__bf16)hi.w;                         \
} while (0)

#define COMPUTE(a0, a1, a2, a3, b0, b1, b2, b3, b4, b5, b6, b7) do {    \
    bf16x8 af_;                                                         \
    CVT8(af_, a0, a1);                                                  \
    acc0 = MFMA_(af_, b0, acc0, 0, 0, 0);                               \
    acc1 = MFMA_(af_, b2, acc1, 0, 0, 0);                               \
    acc2 = MFMA_(af_, b4, acc2, 0, 0, 0);                               \
    acc3 = MFMA_(af_, b6, acc3, 0, 0, 0);                               \
    CVT8(af_, a2, a3);                                                  \
    acc0 = MFMA_(af_, b1, acc0, 0, 0, 0);                               \
    acc1 = MFMA_(af_, b3, acc1, 0, 0, 0);                               \
    acc2 = MFMA_(af_, b5, acc2, 0, 0, 0);                               \
    acc3 = MFMA_(af_, b7, acc3, 0, 0, 0);                               \
} while (0)

// one pair of K-steps: compute bank X (step t), refill X for t+2,
// compute bank Y (step t+1), refill Y for t+3
#define STEP2(t)                                                        \
    COMPUTE(ax0, ax1, ax2, ax3, bx0, bx1, bx2, bx3, bx4, bx5, bx6, bx7);\
    if ((t) + 2 < NTT) { LOADA((t)+2, ax0, ax1, ax2, ax3);              \
                         LOADB((t)+2, bx0, bx1, bx2, bx3, bx4, bx5, bx6, bx7); } \
    COMPUTE(ay0, ay1, ay2, ay3, by0, by1, by2, by3, by4, by5, by6, by7);\
    if ((t) + 3 < NTT) { LOADA((t)+3, ay0, ay1, ay2, ay3);              \
                         LOADB((t)+3, by0, by1, by2, by3, by4, by5, by6, by7); }

__global__ __launch_bounds__(384) void k_item_gemm_reg2(
    const float* __restrict__ xt, const float* __restrict__ xi, const float* __restrict__ xs,
    const unsigned short* __restrict__ Wtb,
    const float* __restrict__ bt, const float* __restrict__ bi, const float* __restrict__ bst,
    unsigned short* __restrict__ Xbs) {
    const int tid  = threadIdx.x;
    const int w    = tid >> 6;          // 0..5
    const int lane = tid & 63;
    const int l16  = lane & 15;
    const int quad = lane >> 4;
    const int rg   = w & 1;             // 16-row group
    const int ng   = w >> 1;            // 0..2 (64-col group)
    const int row0 = blockIdx.x * BM;

    int gr = row0 + rg * 16 + l16;
    if (gr >= N_ITEMS) gr = N_ITEMS - 1;   // dup last row; C-write guarded

    const float* at  = xt + (size_t)gr * 768 + quad * 8;
    const float* ai  = xi + (size_t)gr * 512 + quad * 8;
    const float* as_ = xs + (size_t)gr * 128 + quad * 8;

    const unsigned short* bb0 = Wtb + (size_t)(ng * 64 +  0 + l16) * KK_TOT + quad * 8;
    const unsigned short* bb1 = Wtb + (size_t)(ng * 64 + 16 + l16) * KK_TOT + quad * 8;
    const unsigned short* bb2 = Wtb + (size_t)(ng * 64 + 32 + l16) * KK_TOT + quad * 8;
    const unsigned short* bb3 = Wtb + (size_t)(ng * 64 + 48 + l16) * KK_TOT + quad * 8;

    f32x4 acc0 = (f32x4){0.f, 0.f, 0.f, 0.f};
    f32x4 acc1 = acc0, acc2 = acc0, acc3 = acc0;

    float4 ax0, ax1, ax2, ax3, ay0, ay1, ay2, ay3;
    bf16x8 bx0, bx1, bx2, bx3, bx4, bx5, bx6, bx7;
    bf16x8 by0, by1, by2, by3, by4, by5, by6, by7;

    LOADA(0, ax0, ax1, ax2, ax3);
    LOADB(0, bx0, bx1, bx2, bx3, bx4, bx5, bx6, bx7);
    LOADA(1, ay0, ay1, ay2, ay3);
    LOADB(1, by0, by1, by2, by3, by4, by5, by6, by7);

    STEP2(0)  STEP2(2)  STEP2(4)  STEP2(6)  STEP2(8)
    STEP2(10) STEP2(12) STEP2(14) STEP2(16) STEP2(18) STEP2(20)

    // epilogue: bias + bf16 store
#pragma unroll
    for (int tn = 0; tn < 4; tn++) {
        f32x4 a = (tn == 0) ? acc0 : (tn == 1) ? acc1 : (tn == 2) ? acc2 : acc3;
        int n = ng * 64 + tn * 16 + l16;    // 0..191
        int b = n >> 6, d = n & 63;
        float bias = bt[b * 64 + d] + bi[b * 64 + d] + bst[b * 64 + d];
#pragma unroll
        for (int r = 0; r < 4; r++) {
            int row = row0 + rg * 16 + quad * 4 + r;
            if (row < N_ITEMS) {
                Xbs[(size_t)(N_USERS + row) * FF + n] = f2bf(a[r] + bias);
            }
        }
    }
}

// ---------------- SPMM bf16 gather, 4-wide unroll ----------------
// weight factored: y[n] = rsq[n] * sum_d rsq[d] * x[d]; rsq is a 360 KB
// L2-resident table, per-edge value broadcast across the half-block.
__global__ __launch_bounds__(192) void k_spmm_bf(const unsigned int* __restrict__ Xb,
                                                 unsigned int* __restrict__ Yb,
                                                 const int* __restrict__ offs,
                                                 const int* __restrict__ deg,
                                                 const int* __restrict__ edst,
                                                 const float* __restrict__ rsq) {
    int t = threadIdx.x;
    int half = (t >= FH) ? 1 : 0;
    int c = t - half * FH;
    int n = blockIdx.x * 2 + half;
    int start = offs[n];
    int dg = deg[n];
    const int* ed = edst + start;
    float a0 = 0.f, a1 = 0.f;
    for (int j = 0; j < dg; j += 4) {
        int last = dg - 1;
        int j1 = (j + 1 < dg) ? j + 1 : last;
        int j2 = (j + 2 < dg) ? j + 2 : last;
        int j3 = (j + 3 < dg) ? j + 3 : last;
        int d0 = ed[j], d1 = ed[j1], d2 = ed[j2], d3 = ed[j3];
        float v0 = rsq[d0];
        float v1 = (j + 1 < dg) ? rsq[d1] : 0.f;
        float v2 = (j + 2 < dg) ? rsq[d2] : 0.f;
        float v3 = (j + 3 < dg) ? rsq[d3] : 0.f;
        unsigned int x0 = Xb[(size_t)d0 * FH + c];
        unsigned int x1 = Xb[(size_t)d1 * FH + c];
        unsigned int x2 = Xb[(size_t)d2 * FH + c];
        unsigned int x3 = Xb[(size_t)d3 * FH + c];
        a0 = fmaf(v0, bf_lo(x0), a0); a1 = fmaf(v0, bf_hi(x0), a1);
        a0 = fmaf(v1, bf_lo(x1), a0); a1 = fmaf(v1, bf_hi(x1), a1);
        a0 = fmaf(v2, bf_lo(x2), a0); a1 = fmaf(v2, bf_hi(x2), a1);
        a0 = fmaf(v3, bf_lo(x3), a0); a1 = fmaf(v3, bf_hi(x3), a1);
    }
    float rs = rsq[n];
    Yb[(size_t)n * FH + c] = pack2(a0 * rs, a1 * rs);
}

// ---------------- attention: sum 3 bf16 layers + MFMA MLP + readout --------
#define LDA 200

__global__ __launch_bounds__(256) void k_attn_mfma(
    const unsigned int* __restrict__ X0,      // layer-0 bf16 pairs
    const unsigned int* __restrict__ X1,      // layer-1
    const unsigned int* __restrict__ X2,      // layer-2
    const unsigned short* __restrict__ W1T,   // 128 x 192 bf16 (pre-transposed)
    const float* __restrict__ B1,             // 128
    const float* __restrict__ W2,             // 128 x 3
    const float* __restrict__ B2,             // 3
    float* __restrict__ out,
    int node_base, int n_rows) {
    __shared__ unsigned short Atile[64 * LDA];
    __shared__ float aws[64][4];
    const int tid  = threadIdx.x;
    const int wave = tid >> 6;
    const int lane = tid & 63;
    const int row0 = blockIdx.x * 64;
    const float inv3 = 1.f / 3.f;

    // stage A: 64 rows x 96 uint-pairs; sum three bf16 layers in fp32, /3
#pragma unroll
    for (int i = 0; i < 6; i++) {
        int id = tid + i * 256;            // 0..1535
        int r = id / 24;
        int q = id - r * 24;               // uint group: 4 uints = 8 bf16 cols
        u16x8 pk;
        if (row0 + r < n_rows) {
            size_t base = (size_t)(node_base + row0 + r) * FH + q * 4;
            uint4 a = *(const uint4*)(X0 + base);
            uint4 b = *(const uint4*)(X1 + base);
            uint4 c = *(const uint4*)(X2 + base);
            pk[0] = f2bf((bf_lo(a.x) + bf_lo(b.x) + bf_lo(c.x)) * inv3);
            pk[1] = f2bf((bf_hi(a.x) + bf_hi(b.x) + bf_hi(c.x)) * inv3);
            pk[2] = f2bf((bf_lo(a.y) + bf_lo(b.y) + bf_lo(c.y)) * inv3);
            pk[3] = f2bf((bf_hi(a.y) + bf_hi(b.y) + bf_hi(c.y)) * inv3);
            pk[4] = f2bf((bf_lo(a.z) + bf_lo(b.z) + bf_lo(c.z)) * inv3);
            pk[5] = f2bf((bf_hi(a.z) + bf_hi(b.z) + bf_hi(c.z)) * inv3);
            pk[6] = f2bf((bf_lo(a.w) + bf_lo(b.w) + bf_lo(c.w)) * inv3);
            pk[7] = f2bf((bf_hi(a.w) + bf_hi(b.w) + bf_hi(c.w)) * inv3);
        } else {
            pk = (u16x8){0, 0, 0, 0, 0, 0, 0, 0};
        }
        *(u16x8*)(&Atile[r * LDA + q * 8]) = pk;
    }
    __syncthreads();

    f32x4 acc[8];
#pragma unroll
    for (int tn = 0; tn < 8; tn++) acc[tn] = (f32x4){0.f, 0.f, 0.f, 0.f};
    const int l16 = lane & 15;
    const int quad = lane >> 4;
#pragma unroll
    for (int kk = 0; kk < FF; kk += 32) {
        bf16x8 af = *(const bf16x8*)(&Atile[(wave * 16 + l16) * LDA + kk + quad * 8]);
#pragma unroll
        for (int tn = 0; tn < 8; tn++) {
            bf16x8 bf = *(const bf16x8*)(&W1T[(size_t)(tn * 16 + l16) * FF + kk + quad * 8]);
            acc[tn] = __builtin_amdgcn_mfma_f32_16x16x32_bf16(af, bf, acc[tn], 0, 0, 0);
        }
    }

    float pl[4][3];
#pragma unroll
    for (int r = 0; r < 4; r++) { pl[r][0] = 0.f; pl[r][1] = 0.f; pl[r][2] = 0.f; }
#pragma unroll
    for (int tn = 0; tn < 8; tn++) {
        int col = tn * 16 + l16;
        float b1v = B1[col];
        float w0 = W2[col * 3 + 0], w1 = W2[col * 3 + 1], w2v = W2[col * 3 + 2];
#pragma unroll
        for (int r = 0; r < 4; r++) {
            float h = fmaxf(acc[tn][r] + b1v, 0.f);
            pl[r][0] = fmaf(h, w0, pl[r][0]);
            pl[r][1] = fmaf(h, w1, pl[r][1]);
            pl[r][2] = fmaf(h, w2v, pl[r][2]);
        }
    }
#pragma unroll
    for (int m = 1; m <= 8; m <<= 1) {
#pragma unroll
        for (int r = 0; r < 4; r++) {
            pl[r][0] += __shfl_xor(pl[r][0], m, 64);
            pl[r][1] += __shfl_xor(pl[r][1], m, 64);
            pl[r][2] += __shfl_xor(pl[r][2], m, 64);
        }
    }
    float b20 = B2[0], b21 = B2[1], b22 = B2[2];
    if (l16 == 0) {
#pragma unroll
        for (int r = 0; r < 4; r++) {
            float l0 = pl[r][0] + b20, l1 = pl[r][1] + b21, l2 = pl[r][2] + b22;
            float mx = fmaxf(l0, fmaxf(l1, l2));
            float e0 = __expf(l0 - mx), e1 = __expf(l1 - mx), e2 = __expf(l2 - mx);
            float inv = 1.f / (e0 + e1 + e2);
            int rr = wave * 16 + quad * 4 + r;
            aws[rr][0] = e0 * inv; aws[rr][1] = e1 * inv; aws[rr][2] = e2 * inv;
        }
    }
    __syncthreads();

#pragma unroll
    for (int i = 0; i < 16; i++) {
        int flat = tid + i * 256;
        int r = flat >> 6, d = flat & 63;
        if (row0 + r < n_rows) {
            float a0 = aws[r][0], a1 = aws[r][1], a2 = aws[r][2];
            const unsigned short* Ar = &Atile[r * LDA];
            float v = a0 * bf2f(Ar[d]) + a1 * bf2f(Ar[64 + d]) + a2 * bf2f(Ar[128 + d]);
            out[(size_t)(node_base + row0 + r) * DD + d] = v;
        }
    }
}

// ---------------- launch ----------------
extern "C" void kernel_launch(void* const* d_in, const int* in_sizes, int n_in,
                              void* d_out, int out_size, void* d_ws, size_t ws_size,
                              hipStream_t stream) {
    (void)in_sizes; (void)n_in; (void)out_size; (void)ws_size;
    const float* x_txt    = (const float*)d_in[0];
    const float* x_img    = (const float*)d_in[1];
    const float* x_struct = (const float*)d_in[2];
    const float* user_emb = (const float*)d_in[3];
    const float* W_txt    = (const float*)d_in[4];
    const float* b_txt    = (const float*)d_in[5];
    const float* W_img    = (const float*)d_in[6];
    const float* b_img    = (const float*)d_in[7];
    const float* W_st     = (const float*)d_in[8];
    const float* b_st     = (const float*)d_in[9];
    const float* Wu1      = (const float*)d_in[10];
    const float* bu1      = (const float*)d_in[11];
    const float* Wu2      = (const float*)d_in[12];
    const float* bu2      = (const float*)d_in[13];
    const float* Wi1      = (const float*)d_in[14];
    const float* bi1      = (const float*)d_in[15];
    const float* Wi2      = (const float*)d_in[16];
    const float* bi2      = (const float*)d_in[17];
    const int*   ei       = (const int*)d_in[18];
    float* out = (float*)d_out;

    char* base = (char*)d_ws;
    size_t off = 0;
    auto take = [&](size_t bytes) -> void* {
        void* p = base + off;
        off += (bytes + 255) & ~(size_t)255;
        return p;
    };
    unsigned int* Xb0  = (unsigned int*)take((size_t)N_NODES * FH * 4);
    unsigned int* Yb   = (unsigned int*)take((size_t)N_NODES * FH * 4);
    unsigned int* Zb   = (unsigned int*)take((size_t)N_NODES * FH * 4);
    int* deg    = (int*)take((size_t)N_NODES * 4);
    int* offs   = (int*)take((size_t)SCAN_NBLK * 1024 * 4);
    int* cursor = (int*)take((size_t)N_NODES * 4);
    int* bsum   = (int*)take((size_t)SCAN_NBLK * 4);
    int* bscan  = (int*)take((size_t)SCAN_NBLK * 4);
    float* rsq  = (float*)take((size_t)N_NODES * 4);
    int* edst   = (int*)take((size_t)E_DIR * 4);
    int* mode   = (int*)take(256);
    unsigned short* Wtb  = (unsigned short*)take((size_t)FF * KK_TOT * 2);
    unsigned short* W1Tu = (unsigned short*)take((size_t)128 * FF * 2);
    unsigned short* W1Ti = (unsigned short*)take((size_t)128 * FF * 2);

    hipMemsetAsync(deg, 0, (size_t)N_NODES * 4, stream);

    k_mode<<<1, 256, 0, stream>>>(ei, mode);
    k_deg<<<(E_UND + 255) / 256, 256, 0, stream>>>(ei, mode, deg);
    k_scan1<<<SCAN_NBLK, 1024, 0, stream>>>(deg, offs, bsum);
    k_scan2<<<1, 64, 0, stream>>>(bsum, bscan);
    k_scan3<<<(N_NODES + 255) / 256, 256, 0, stream>>>(deg, offs, bscan, cursor, rsq);
    k_fill<<<(E_DIR + 255) / 256, 256, 0, stream>>>(ei, mode, cursor, edst);

    k_users<<<(N_USERS * FF + 255) / 256, 256, 0, stream>>>(user_emb,
                                                            (unsigned short*)Xb0);
    k_cvt_w<<<(FF * KK_TOT + 255) / 256, 256, 0, stream>>>(W_txt, W_img, W_st, Wtb);
    k_cvt_w1<<<(128 * FF + 255) / 256, 256, 0, stream>>>(Wu1, Wi1, W1Tu, W1Ti);
    k_item_gemm_reg2<<<(N_ITEMS + BM - 1) / BM, 384, 0, stream>>>(
        x_txt, x_img, x_struct, Wtb, b_txt, b_img, b_st, (unsigned short*)Xb0);

    k_spmm_bf<<<N_NODES / 2, 192, 0, stream>>>(Xb0, Yb, offs, deg, edst, rsq);
    k_spmm_bf<<<N_NODES / 2, 192, 0, stream>>>(Yb, Zb, offs, deg, edst, rsq);

    k_attn_mfma<<<(N_USERS + 63) / 64, 256, 0, stream>>>(
        Xb0, Yb, Zb, W1Tu, bu1, Wu2, bu2, out, 0, N_USERS);
    k_attn_mfma<<<(N_ITEMS + 63) / 64, 256, 0, stream>>>(
        Xb0, Yb, Zb, W1Ti, bi1, Wi2, bi2, out, N_USERS, N_ITEMS);
}

// Round 6
// 665.599 us; speedup vs baseline: 1.1919x; 1.1888x over previous
//
#include <hip/hip_runtime.h>
#include <math.h>

#define N_USERS 60000
#define N_ITEMS 30000
#define N_NODES 90000
#define DD 64
#define FF 192              // 3*DD
#define FH 96               // FF/2 (bf16 pairs per row)
#define KK_TOT 1408         // 768 + 512 + 128
#define E_UND 500000
#define E_DIR 1000000
#define SCAN_NBLK 88        // ceil(90000/1024)

typedef __attribute__((ext_vector_type(8))) __bf16 bf16x8;
typedef __attribute__((ext_vector_type(8))) unsigned short u16x8;
typedef __attribute__((ext_vector_type(4))) float f32x4;

typedef __attribute__((address_space(1))) const void gvoid;
typedef __attribute__((address_space(3))) void svoid;

__device__ __forceinline__ void gll16(const void* g, void* l) {
    // async global->LDS DMA, 16B per lane; LDS dest = uniform base + lane*16
    // NOTE: not sinkable by the scheduler (LDS side effect) — this is why
    // this staging survives codegen where plain register loads (r4/r5) were
    // serialized into load->use at VGPR_Count=32.
    __builtin_amdgcn_global_load_lds((gvoid*)g, (svoid*)l, 16, 0, 0);
}
__device__ __forceinline__ void fence_bar() {
    asm volatile("" ::: "memory");
    __builtin_amdgcn_s_barrier();
    asm volatile("" ::: "memory");
}

__device__ __forceinline__ unsigned short f2bf(float f) {
    unsigned int u = __float_as_uint(f);
    unsigned int r = (u + 0x7FFFu + ((u >> 16) & 1u)) >> 16;   // RNE
    return (unsigned short)r;
}
__device__ __forceinline__ float bf_lo(unsigned int x) { return __uint_as_float(x << 16); }
__device__ __forceinline__ float bf_hi(unsigned int x) { return __uint_as_float(x & 0xFFFF0000u); }
__device__ __forceinline__ float bf2f(unsigned short x) {
    return __uint_as_float((unsigned int)x << 16);
}
__device__ __forceinline__ unsigned int pack2(float a, float b) {
    return ((unsigned int)f2bf(b) << 16) | (unsigned int)f2bf(a);
}

// ---------------- edge-layout probe: int32 vs int64 storage ----------------
__global__ void k_mode(const int* __restrict__ ei, int* __restrict__ mode) {
    __shared__ int any;
    if (threadIdx.x == 0) any = 0;
    __syncthreads();
    if (ei[2 * threadIdx.x + 1] != 0) atomicOr(&any, 1);
    __syncthreads();
    if (threadIdx.x == 0) mode[0] = (any == 0) ? 1 : 0;   // 1 => int64 layout
}

__device__ __forceinline__ void load_pair(const int* __restrict__ ei, int md, int u,
                                          int& a, int& b) {
    if (md) { a = ei[2 * u]; b = ei[2 * (E_UND + u)]; }
    else    { a = ei[u];     b = ei[E_UND + u]; }
}

// ---------------- degree count ----------------
__global__ void k_deg(const int* __restrict__ ei, const int* __restrict__ mode,
                      int* __restrict__ deg) {
    int i = blockIdx.x * 256 + threadIdx.x;
    if (i >= E_UND) return;
    int md = mode[0];
    int a, b;
    load_pair(ei, md, i, a, b);
    atomicAdd(&deg[a], 1);
    atomicAdd(&deg[b], 1);
}

// ---------------- exclusive scan (3 kernels) ----------------
__global__ __launch_bounds__(1024) void k_scan1(const int* __restrict__ deg,
                                                int* __restrict__ offs,
                                                int* __restrict__ bsum) {
    __shared__ int tmp[1024];
    int b = blockIdx.x, t = threadIdx.x;
    int i = b * 1024 + t;
    int v = (i < N_NODES) ? deg[i] : 0;
    tmp[t] = v;
    __syncthreads();
    for (int off = 1; off < 1024; off <<= 1) {
        int add = (t >= off) ? tmp[t - off] : 0;
        __syncthreads();
        tmp[t] += add;
        __syncthreads();
    }
    offs[i] = tmp[t] - v;              // exclusive within block
    if (t == 1023) bsum[b] = tmp[t];
}

__global__ void k_scan2(const int* __restrict__ bsum, int* __restrict__ bscan) {
    if (threadIdx.x == 0) {
        int run = 0;
        for (int b = 0; b < SCAN_NBLK; b++) { bscan[b] = run; run += bsum[b]; }
    }
}

__global__ void k_scan3(const int* __restrict__ deg, int* __restrict__ offs,
                        const int* __restrict__ bscan, int* __restrict__ cursor,
                        float* __restrict__ rsq) {
    int i = blockIdx.x * 256 + threadIdx.x;
    if (i >= N_NODES) return;
    int o = offs[i] + bscan[i >> 10];
    offs[i] = o;
    cursor[i] = o;
    int dg = deg[i];
    if (dg < 1) dg = 1;
    rsq[i] = rsqrtf((float)dg);
}

// ---------------- CSR fill (counting-sort scatter, dst only) ----------------
__global__ void k_fill(const int* __restrict__ ei, const int* __restrict__ mode,
                       int* __restrict__ cursor,
                       int* __restrict__ edst) {
    int i = blockIdx.x * 256 + threadIdx.x;
    if (i >= E_DIR) return;
    int md = mode[0];
    int u = (i < E_UND) ? i : i - E_UND;
    int a, b;
    load_pair(ei, md, u, a, b);
    int s, d;
    if (i < E_UND) { s = a; d = b; } else { s = b; d = a; }
    int slot = atomicAdd(&cursor[s], 1);
    edst[slot] = d;
}

// ---------------- user rows: transpose copy into bf16 Xb ----------------
__global__ void k_users(const float* __restrict__ ue, unsigned short* __restrict__ Xbs) {
    int idx = blockIdx.x * 256 + threadIdx.x;
    if (idx >= N_USERS * FF) return;
    int n = idx / FF;
    int r = idx - n * FF;
    int b = r >> 6, d = r & 63;
    Xbs[idx] = f2bf(ue[((size_t)b * N_USERS + n) * DD + d]);
}

// ---------------- W transpose+concat+bf16: Wtb[n][k], n=b*64+d ----------------
__global__ void k_cvt_w(const float* __restrict__ Wt, const float* __restrict__ Wi,
                        const float* __restrict__ Wst, unsigned short* __restrict__ Wtb) {
    int idx = blockIdx.x * 256 + threadIdx.x;
    if (idx >= FF * KK_TOT) return;
    int n = idx / KK_TOT;
    int k = idx - n * KK_TOT;
    int b = n >> 6, d = n & 63;
    float v;
    if (k < 768)       v = Wt [((size_t)b * 768 + k) * 64 + d];
    else if (k < 1280) v = Wi [((size_t)b * 512 + (k - 768)) * 64 + d];
    else               v = Wst[((size_t)b * 128 + (k - 1280)) * 64 + d];
    Wtb[idx] = f2bf(v);
}

// ---------------- W1 transpose to bf16: W1T[n][k] = W1[k][n], 128x192 -------
__global__ void k_cvt_w1(const float* __restrict__ Wu1, const float* __restrict__ Wi1,
                         unsigned short* __restrict__ W1Tu,
                         unsigned short* __restrict__ W1Ti) {
    int idx = blockIdx.x * 256 + threadIdx.x;
    if (idx >= 128 * FF) return;
    int n = idx / FF;
    int k = idx - n * FF;
    W1Tu[idx] = f2bf(Wu1[(size_t)k * 128 + n]);
    W1Ti[idx] = f2bf(Wi1[(size_t)k * 128 + n]);
}

// ---------------- item feature GEMM ----------------
// r3 structure (proven: 74 us, 0 bank conflicts) re-parameterized for TLP:
// BM=32 rows x 96-col N-half per block, 4 waves (256 thr). LDS per buffer =
// A 8 KB (fp32) + B 12 KB (bf16) = 20 KB; x2 dbuf = 40 KB -> 4 blocks/CU.
// Grid 1876 blocks (= 7.3/CU) vs r3's 469 (1.8/CU): cross-block TLP hides
// the per-step staging latency the 1-deep pipeline exposes. Adjacent block
// pairs share A rows (L2/L3 absorbs the duplicate A read, r0-verified).
// Counted s_waitcnt vmcnt(5) + raw barriers; both-sides XOR chunk swizzle.
#define BM 32
#define BNH 96
#define BK 64
#define NT (KK_TOT / BK)    // 22

__global__ __launch_bounds__(256, 4) void k_item_gemm_ns(
    const float* __restrict__ xt, const float* __restrict__ xi, const float* __restrict__ xs,
    const unsigned short* __restrict__ Wtb,
    const float* __restrict__ bt, const float* __restrict__ bi, const float* __restrict__ bst,
    unsigned short* __restrict__ Xbs) {
    __shared__ float          Ashf[2][BM * BK];    // 2 x 8 KB, fp32, chunk-swizzled
    __shared__ unsigned short Bsh [2][BNH * BK];   // 2 x 12 KB, bf16, chunk-swizzled
    const int tid  = threadIdx.x;
    const int w    = tid >> 6;          // 0..3
    const int lane = tid & 63;
    const int l16  = lane & 15;
    const int quad = lane >> 4;
    const int rg   = w & 1;             // 16-row group
    const int ng   = w >> 1;            // 48-col half of the 96
    const int row0 = (blockIdx.x >> 1) * BM;
    const int n0g  = (blockIdx.x & 1) * BNH;

    const int ac = lane & 15;           // A 16B-chunk within 256B row
    const int bc = lane & 7;            // B 16B-chunk within 128B row

    auto stage = [&](int k0, int buf) {
        // A: 32 rows x 256B = 8 instrs; wave w does rows [w*8, w*8+8)
#pragma unroll
        for (int i = 0; i < 2; i++) {
            int rb = w * 8 + i * 4;                 // uniform row base
            int r  = rb + (lane >> 4);
            int gr = row0 + r; if (gr >= N_ITEMS) gr = N_ITEMS - 1;
            const float* rp;
            if (k0 < 768)       rp = xt + (size_t)gr * 768 + k0;
            else if (k0 < 1280) rp = xi + (size_t)gr * 512 + (k0 - 768);
            else                rp = xs + (size_t)gr * 128 + (k0 - 1280);
            gll16(rp + ((ac ^ (r & 15)) << 2), &Ashf[buf][rb * BK]);
        }
        // B: 96 rows x 128B = 12 instrs; wave w does rows [w*24, w*24+24)
#pragma unroll
        for (int j = 0; j < 3; j++) {
            int rb = w * 24 + j * 8;                // uniform row base
            int r  = rb + (lane >> 3);
            gll16(Wtb + (size_t)(n0g + r) * KK_TOT + k0 + ((bc ^ (r & 7)) << 3),
                  &Bsh[buf][rb * BK]);
        }
    };

    f32x4 acc[3];
#pragma unroll
    for (int tn = 0; tn < 3; tn++) acc[tn] = (f32x4){0.f, 0.f, 0.f, 0.f};

    auto compute = [&](int buf) {
#pragma unroll
        for (int kk = 0; kk < BK; kk += 32) {
            const int rA = rg * 16 + l16;           // rA & 15 == l16
            const float* Ab = &Ashf[buf][rA * BK];
            const int c0 = (kk >> 2) + quad * 2;    // 16B chunk of k=kk+quad*8
            float4 a0 = *(const float4*)(Ab + (((c0    ) ^ l16) << 2));
            float4 a1 = *(const float4*)(Ab + (((c0 + 1) ^ l16) << 2));
            bf16x8 af;
            af[0] = (__bf16)a0.x; af[1] = (__bf16)a0.y;
            af[2] = (__bf16)a0.z; af[3] = (__bf16)a0.w;
            af[4] = (__bf16)a1.x; af[5] = (__bf16)a1.y;
            af[6] = (__bf16)a1.z; af[7] = (__bf16)a1.w;
            const int cB = (kk >> 3) + quad;
#pragma unroll
            for (int tn = 0; tn < 3; tn++) {
                int R = ng * 48 + tn * 16 + l16;    // R & 7 == l16 & 7
                bf16x8 bfrag = *(const bf16x8*)(&Bsh[buf][R * BK + ((cB ^ (R & 7)) << 3)]);
                acc[tn] = __builtin_amdgcn_mfma_f32_16x16x32_bf16(af, bfrag, acc[tn], 0, 0, 0);
            }
        }
    };

    stage(0, 0);
    int cur = 0;
#pragma unroll 1
    for (int t = 0; t < NT - 1; ++t) {
        fence_bar();                         // all waves done reading buf^1 (compute t-1)
        stage((t + 1) * BK, cur ^ 1);        // 5 gll per wave, stay in flight
        asm volatile("s_waitcnt vmcnt(5)" ::: "memory");   // own tile-t loads landed
        fence_bar();                         // all waves' tile-t loads landed
        compute(cur);
        cur ^= 1;
    }
    fence_bar();
    asm volatile("s_waitcnt vmcnt(0)" ::: "memory");
    fence_bar();
    compute(cur);

    // epilogue: bias + bf16 store
#pragma unroll
    for (int tn = 0; tn < 3; tn++) {
        int n = n0g + ng * 48 + tn * 16 + l16;    // 0..191
        int b = n >> 6, d = n & 63;
        float bias = bt[b * 64 + d] + bi[b * 64 + d] + bst[b * 64 + d];
#pragma unroll
        for (int r = 0; r < 4; r++) {
            int row = row0 + rg * 16 + quad * 4 + r;
            if (row < N_ITEMS) {
                Xbs[(size_t)(N_USERS + row) * FF + n] = f2bf(acc[tn][r] + bias);
            }
        }
    }
}

// ---------------- SPMM bf16 gather, 4-wide unroll ----------------
// weight factored: y[n] = rsq[n] * sum_d rsq[d] * x[d]; rsq is a 360 KB
// L2-resident table, per-edge value broadcast across the half-block.
__global__ __launch_bounds__(192) void k_spmm_bf(const unsigned int* __restrict__ Xb,
                                                 unsigned int* __restrict__ Yb,
                                                 const int* __restrict__ offs,
                                                 const int* __restrict__ deg,
                                                 const int* __restrict__ edst,
                                                 const float* __restrict__ rsq) {
    int t = threadIdx.x;
    int half = (t >= FH) ? 1 : 0;
    int c = t - half * FH;
    int n = blockIdx.x * 2 + half;
    int start = offs[n];
    int dg = deg[n];
    const int* ed = edst + start;
    float a0 = 0.f, a1 = 0.f;
    for (int j = 0; j < dg; j += 4) {
        int last = dg - 1;
        int j1 = (j + 1 < dg) ? j + 1 : last;
        int j2 = (j + 2 < dg) ? j + 2 : last;
        int j3 = (j + 3 < dg) ? j + 3 : last;
        int d0 = ed[j], d1 = ed[j1], d2 = ed[j2], d3 = ed[j3];
        float v0 = rsq[d0];
        float v1 = (j + 1 < dg) ? rsq[d1] : 0.f;
        float v2 = (j + 2 < dg) ? rsq[d2] : 0.f;
        float v3 = (j + 3 < dg) ? rsq[d3] : 0.f;
        unsigned int x0 = Xb[(size_t)d0 * FH + c];
        unsigned int x1 = Xb[(size_t)d1 * FH + c];
        unsigned int x2 = Xb[(size_t)d2 * FH + c];
        unsigned int x3 = Xb[(size_t)d3 * FH + c];
        a0 = fmaf(v0, bf_lo(x0), a0); a1 = fmaf(v0, bf_hi(x0), a1);
        a0 = fmaf(v1, bf_lo(x1), a0); a1 = fmaf(v1, bf_hi(x1), a1);
        a0 = fmaf(v2, bf_lo(x2), a0); a1 = fmaf(v2, bf_hi(x2), a1);
        a0 = fmaf(v3, bf_lo(x3), a0); a1 = fmaf(v3, bf_hi(x3), a1);
    }
    float rs = rsq[n];
    Yb[(size_t)n * FH + c] = pack2(a0 * rs, a1 * rs);
}

// ---------------- attention: sum 3 bf16 layers + MFMA MLP + readout --------
#define LDA 200

__global__ __launch_bounds__(256) void k_attn_mfma(
    const unsigned int* __restrict__ X0,      // layer-0 bf16 pairs
    const unsigned int* __restrict__ X1,      // layer-1
    const unsigned int* __restrict__ X2,      // layer-2
    const unsigned short* __restrict__ W1T,   // 128 x 192 bf16 (pre-transposed)
    const float* __restrict__ B1,             // 128
    const float* __restrict__ W2,             // 128 x 3
    const float* __restrict__ B2,             // 3
    float* __restrict__ out,
    int node_base, int n_rows) {
    __shared__ unsigned short Atile[64 * LDA];
    __shared__ float aws[64][4];
    const int tid  = threadIdx.x;
    const int wave = tid >> 6;
    const int lane = tid & 63;
    const int row0 = blockIdx.x * 64;
    const float inv3 = 1.f / 3.f;

    // stage A: 64 rows x 96 uint-pairs; sum three bf16 layers in fp32, /3
#pragma unroll
    for (int i = 0; i < 6; i++) {
        int id = tid + i * 256;            // 0..1535
        int r = id / 24;
        int q = id - r * 24;               // uint group: 4 uints = 8 bf16 cols
        u16x8 pk;
        if (row0 + r < n_rows) {
            size_t base = (size_t)(node_base + row0 + r) * FH + q * 4;
            uint4 a = *(const uint4*)(X0 + base);
            uint4 b = *(const uint4*)(X1 + base);
            uint4 c = *(const uint4*)(X2 + base);
            pk[0] = f2bf((bf_lo(a.x) + bf_lo(b.x) + bf_lo(c.x)) * inv3);
            pk[1] = f2bf((bf_hi(a.x) + bf_hi(b.x) + bf_hi(c.x)) * inv3);
            pk[2] = f2bf((bf_lo(a.y) + bf_lo(b.y) + bf_lo(c.y)) * inv3);
            pk[3] = f2bf((bf_hi(a.y) + bf_hi(b.y) + bf_hi(c.y)) * inv3);
            pk[4] = f2bf((bf_lo(a.z) + bf_lo(b.z) + bf_lo(c.z)) * inv3);
            pk[5] = f2bf((bf_hi(a.z) + bf_hi(b.z) + bf_hi(c.z)) * inv3);
            pk[6] = f2bf((bf_lo(a.w) + bf_lo(b.w) + bf_lo(c.w)) * inv3);
            pk[7] = f2bf((bf_hi(a.w) + bf_hi(b.w) + bf_hi(c.w)) * inv3);
        } else {
            pk = (u16x8){0, 0, 0, 0, 0, 0, 0, 0};
        }
        *(u16x8*)(&Atile[r * LDA + q * 8]) = pk;
    }
    __syncthreads();

    f32x4 acc[8];
#pragma unroll
    for (int tn = 0; tn < 8; tn++) acc[tn] = (f32x4){0.f, 0.f, 0.f, 0.f};
    const int l16 = lane & 15;
    const int quad = lane >> 4;
#pragma unroll
    for (int kk = 0; kk < FF; kk += 32) {
        bf16x8 af = *(const bf16x8*)(&Atile[(wave * 16 + l16) * LDA + kk + quad * 8]);
#pragma unroll
        for (int tn = 0; tn < 8; tn++) {
            bf16x8 bf = *(const bf16x8*)(&W1T[(size_t)(tn * 16 + l16) * FF + kk + quad * 8]);
            acc[tn] = __builtin_amdgcn_mfma_f32_16x16x32_bf16(af, bf, acc[tn], 0, 0, 0);
        }
    }

    float pl[4][3];
#pragma unroll
    for (int r = 0; r < 4; r++) { pl[r][0] = 0.f; pl[r][1] = 0.f; pl[r][2] = 0.f; }
#pragma unroll
    for (int tn = 0; tn < 8; tn++) {
        int col = tn * 16 + l16;
        float b1v = B1[col];
        float w0 = W2[col * 3 + 0], w1 = W2[col * 3 + 1], w2v = W2[col * 3 + 2];
#pragma unroll
        for (int r = 0; r < 4; r++) {
            float h = fmaxf(acc[tn][r] + b1v, 0.f);
            pl[r][0] = fmaf(h, w0, pl[r][0]);
            pl[r][1] = fmaf(h, w1, pl[r][1]);
            pl[r][2] = fmaf(h, w2v, pl[r][2]);
        }
    }
#pragma unroll
    for (int m = 1; m <= 8; m <<= 1) {
#pragma unroll
        for (int r = 0; r < 4; r++) {
            pl[r][0] += __shfl_xor(pl[r][0], m, 64);
            pl[r][1] += __shfl_xor(pl[r][1], m, 64);
            pl[r][2] += __shfl_xor(pl[r][2], m, 64);
        }
    }
    float b20 = B2[0], b21 = B2[1], b22 = B2[2];
    if (l16 == 0) {
#pragma unroll
        for (int r = 0; r < 4; r++) {
            float l0 = pl[r][0] + b20, l1 = pl[r][1] + b21, l2 = pl[r][2] + b22;
            float mx = fmaxf(l0, fmaxf(l1, l2));
            float e0 = __expf(l0 - mx), e1 = __expf(l1 - mx), e2 = __expf(l2 - mx);
            float inv = 1.f / (e0 + e1 + e2);
            int rr = wave * 16 + quad * 4 + r;
            aws[rr][0] = e0 * inv; aws[rr][1] = e1 * inv; aws[rr][2] = e2 * inv;
        }
    }
    __syncthreads();

#pragma unroll
    for (int i = 0; i < 16; i++) {
        int flat = tid + i * 256;
        int r = flat >> 6, d = flat & 63;
        if (row0 + r < n_rows) {
            float a0 = aws[r][0], a1 = aws[r][1], a2 = aws[r][2];
            const unsigned short* Ar = &Atile[r * LDA];
            float v = a0 * bf2f(Ar[d]) + a1 * bf2f(Ar[64 + d]) + a2 * bf2f(Ar[128 + d]);
            out[(size_t)(node_base + row0 + r) * DD + d] = v;
        }
    }
}

// ---------------- launch ----------------
extern "C" void kernel_launch(void* const* d_in, const int* in_sizes, int n_in,
                              void* d_out, int out_size, void* d_ws, size_t ws_size,
                              hipStream_t stream) {
    (void)in_sizes; (void)n_in; (void)out_size; (void)ws_size;
    const float* x_txt    = (const float*)d_in[0];
    const float* x_img    = (const float*)d_in[1];
    const float* x_struct = (const float*)d_in[2];
    const float* user_emb = (const float*)d_in[3];
    const float* W_txt    = (const float*)d_in[4];
    const float* b_txt    = (const float*)d_in[5];
    const float* W_img    = (const float*)d_in[6];
    const float* b_img    = (const float*)d_in[7];
    const float* W_st     = (const float*)d_in[8];
    const float* b_st     = (const float*)d_in[9];
    const float* Wu1      = (const float*)d_in[10];
    const float* bu1      = (const float*)d_in[11];
    const float* Wu2      = (const float*)d_in[12];
    const float* bu2      = (const float*)d_in[13];
    const float* Wi1      = (const float*)d_in[14];
    const float* bi1      = (const float*)d_in[15];
    const float* Wi2      = (const float*)d_in[16];
    const float* bi2      = (const float*)d_in[17];
    const int*   ei       = (const int*)d_in[18];
    float* out = (float*)d_out;

    char* base = (char*)d_ws;
    size_t off = 0;
    auto take = [&](size_t bytes) -> void* {
        void* p = base + off;
        off += (bytes + 255) & ~(size_t)255;
        return p;
    };
    unsigned int* Xb0  = (unsigned int*)take((size_t)N_NODES * FH * 4);
    unsigned int* Yb   = (unsigned int*)take((size_t)N_NODES * FH * 4);
    unsigned int* Zb   = (unsigned int*)take((size_t)N_NODES * FH * 4);
    int* deg    = (int*)take((size_t)N_NODES * 4);
    int* offs   = (int*)take((size_t)SCAN_NBLK * 1024 * 4);
    int* cursor = (int*)take((size_t)N_NODES * 4);
    int* bsum   = (int*)take((size_t)SCAN_NBLK * 4);
    int* bscan  = (int*)take((size_t)SCAN_NBLK * 4);
    float* rsq  = (float*)take((size_t)N_NODES * 4);
    int* edst   = (int*)take((size_t)E_DIR * 4);
    int* mode   = (int*)take(256);
    unsigned short* Wtb  = (unsigned short*)take((size_t)FF * KK_TOT * 2);
    unsigned short* W1Tu = (unsigned short*)take((size_t)128 * FF * 2);
    unsigned short* W1Ti = (unsigned short*)take((size_t)128 * FF * 2);

    hipMemsetAsync(deg, 0, (size_t)N_NODES * 4, stream);

    k_mode<<<1, 256, 0, stream>>>(ei, mode);
    k_deg<<<(E_UND + 255) / 256, 256, 0, stream>>>(ei, mode, deg);
    k_scan1<<<SCAN_NBLK, 1024, 0, stream>>>(deg, offs, bsum);
    k_scan2<<<1, 64, 0, stream>>>(bsum, bscan);
    k_scan3<<<(N_NODES + 255) / 256, 256, 0, stream>>>(deg, offs, bscan, cursor, rsq);
    k_fill<<<(E_DIR + 255) / 256, 256, 0, stream>>>(ei, mode, cursor, edst);

    k_users<<<(N_USERS * FF + 255) / 256, 256, 0, stream>>>(user_emb,
                                                            (unsigned short*)Xb0);
    k_cvt_w<<<(FF * KK_TOT + 255) / 256, 256, 0, stream>>>(W_txt, W_img, W_st, Wtb);
    k_cvt_w1<<<(128 * FF + 255) / 256, 256, 0, stream>>>(Wu1, Wi1, W1Tu, W1Ti);
    k_item_gemm_ns<<<((N_ITEMS + BM - 1) / BM) * 2, 256, 0, stream>>>(
        x_txt, x_img, x_struct, Wtb, b_txt, b_img, b_st, (unsigned short*)Xb0);

    k_spmm_bf<<<N_NODES / 2, 192, 0, stream>>>(Xb0, Yb, offs, deg, edst, rsq);
    k_spmm_bf<<<N_NODES / 2, 192, 0, stream>>>(Yb, Zb, offs, deg, edst, rsq);

    k_attn_mfma<<<(N_USERS + 63) / 64, 256, 0, stream>>>(
        Xb0, Yb, Zb, W1Tu, bu1, Wu2, bu2, out, 0, N_USERS);
    k_attn_mfma<<<(N_ITEMS + 63) / 64, 256, 0, stream>>>(
        Xb0, Yb, Zb, W1Ti, bi1, Wi2, bi2, out, N_USERS, N_ITEMS);
}